// Round 4
// baseline (313.895 us; speedup 1.0000x reference)
//
#include <hip/hip_runtime.h>
#include <hip/hip_bf16.h>
#include <math.h>

#define HIDDEN 256
#define INV_SCALE 0.17677669529663687f  /* 1/sqrt(32) */

typedef __attribute__((ext_vector_type(8))) short short8;
typedef __attribute__((ext_vector_type(4))) float f32x4;
typedef const __attribute__((address_space(1))) unsigned int* gas_ptr;
typedef __attribute__((address_space(3))) unsigned int* las_ptr;

static __device__ __forceinline__ unsigned short f2bf(float x) {
  unsigned u = __float_as_uint(x);
  unsigned r = (u + 0x7FFF + ((u >> 16) & 1)) >> 16;
  return (unsigned short)r;
}
static __device__ __forceinline__ float bf2f(unsigned short u) {
  return __uint_as_float((unsigned)u << 16);
}

// ---------------- input / weight conversion to bf16 ----------------

__global__ __launch_bounds__(256) void conv_a_kernel(const float* __restrict__ in,
                                                     unsigned short* __restrict__ out,
                                                     int total4) {
  int stride = gridDim.x * blockDim.x;
  for (int i = blockIdx.x * blockDim.x + threadIdx.x; i < total4; i += stride) {
    float4 f = ((const float4*)in)[i];
    ushort4 u;
    u.x = f2bf(f.x); u.y = f2bf(f.y); u.z = f2bf(f.z); u.w = f2bf(f.w);
    ((ushort4*)out)[i] = u;
  }
}

// Wq,Wk,Wv -> wqkv[768][256], Wo -> wob[256][256]
__global__ __launch_bounds__(256) void conv_w_kernel(const float* __restrict__ Wq,
                                                     const float* __restrict__ Wk,
                                                     const float* __restrict__ Wv,
                                                     const float* __restrict__ Wo,
                                                     unsigned short* __restrict__ wqkv,
                                                     unsigned short* __restrict__ wob) {
  int i = blockIdx.x * 256 + threadIdx.x;  // grid 1024 -> 262144
  int m = i >> 16;
  int j = i & 65535;
  const float* s = (m == 0) ? Wq : (m == 1) ? Wk : (m == 2) ? Wv : Wo;
  unsigned short b = f2bf(s[j]);
  if (m < 3) wqkv[m * 65536 + j] = b;
  else wob[j] = b;
}

// ---------------- CSR build ----------------

__global__ __launch_bounds__(256) void hist_kernel(const int* __restrict__ dst,
                                                   int* __restrict__ deg, int E) {
  int e = blockIdx.x * blockDim.x + threadIdx.x;
  if (e < E) atomicAdd(&deg[dst[e]], 1);
}

__global__ __launch_bounds__(256) void scan1_kernel(const int* __restrict__ deg,
                                                    int* __restrict__ offs,
                                                    int* __restrict__ bsums, int N) {
  __shared__ int s[256];
  int tid = threadIdx.x;
  int base = blockIdx.x * 1024 + tid * 4;
  int v0 = (base + 0 < N) ? deg[base + 0] : 0;
  int v1 = (base + 1 < N) ? deg[base + 1] : 0;
  int v2 = (base + 2 < N) ? deg[base + 2] : 0;
  int v3 = (base + 3 < N) ? deg[base + 3] : 0;
  int tsum = v0 + v1 + v2 + v3;
  s[tid] = tsum;
  __syncthreads();
  for (int off = 1; off < 256; off <<= 1) {
    int t = (tid >= off) ? s[tid - off] : 0;
    __syncthreads();
    s[tid] += t;
    __syncthreads();
  }
  int excl = s[tid] - tsum;
  if (base + 0 < N) offs[base + 0] = excl;
  if (base + 1 < N) offs[base + 1] = excl + v0;
  if (base + 2 < N) offs[base + 2] = excl + v0 + v1;
  if (base + 3 < N) offs[base + 3] = excl + v0 + v1 + v2;
  if (tid == 255) bsums[blockIdx.x] = s[255];
}

__global__ void scan2_kernel(int* __restrict__ bsums, int nb) {
  if (blockIdx.x == 0 && threadIdx.x == 0) {
    int run = 0;
    for (int b = 0; b < nb; ++b) { int t = bsums[b]; bsums[b] = run; run += t; }
  }
}

__global__ __launch_bounds__(256) void scan3_kernel(int* __restrict__ offs,
                                                    int* __restrict__ cursor,
                                                    const int* __restrict__ bsums,
                                                    int N, int E) {
  int i = blockIdx.x * blockDim.x + threadIdx.x;
  if (i < N) {
    int v = offs[i] + bsums[i >> 10];
    offs[i] = v;
    cursor[i] = v;
  }
  if (i == 0) offs[N] = E;
}

__global__ __launch_bounds__(256) void scatter_kernel(const int* __restrict__ dst,
                                                      const int* __restrict__ src,
                                                      int* __restrict__ cursor,
                                                      int* __restrict__ esrc, int E) {
  int e = blockIdx.x * blockDim.x + threadIdx.x;
  if (e < E) {
    int n = dst[e];
    int pos = atomicAdd(&cursor[n], 1);
    esrc[pos] = src[e];
  }
}

// ---------------- bf16 MFMA GEMM, 2-phase pipelined ----------------
// MODE 0: fused QKV (Ncols=768): cols 0-255 -> q bf16 (+bias), 256-511 -> k bf16, 512-767 -> v bf16
// MODE 1: out projection (Ncols=256): fp32 + bias
#define GBM 128
#define GBN 128
#define GBK 32
#define NKSTEP (HIDDEN / GBK)

template <int MODE>
__global__ __launch_bounds__(256) void mfma_gemm_kernel(const unsigned short* __restrict__ A,
                                                        const unsigned short* __restrict__ B,
                                                        const float* __restrict__ bias,
                                                        float* __restrict__ Cf,
                                                        unsigned short* __restrict__ Cq,
                                                        unsigned short* __restrict__ Ck,
                                                        unsigned short* __restrict__ Cv,
                                                        int M) {
  __shared__ unsigned short As[2][GBM][GBK];
  __shared__ unsigned short Bs[2][GBN][GBK];
  int tid = threadIdx.x;
  int lane = tid & 63;
  int wid = tid >> 6;
  int wm = wid >> 1, wn = wid & 1;
  int brow = blockIdx.x * GBM;
  int bcol = blockIdx.y * GBN;

  // staging: wave wid covers rows [wid*32, wid*32+32): 2 x 1KB per operand
  int srow = wid * 32 + (lane >> 2);
  int skoff = (lane & 3) * 8;
  const unsigned short* gA0 = &A[(size_t)(brow + srow) * HIDDEN + skoff];
  const unsigned short* gB0 = &B[(size_t)(bcol + srow) * HIDDEN + skoff];
  char* ldsA0 = (char*)&As[0][0][0] + wid * 2048;
  char* ldsA1 = (char*)&As[1][0][0] + wid * 2048;
  char* ldsB0 = (char*)&Bs[0][0][0] + wid * 2048;
  char* ldsB1 = (char*)&Bs[1][0][0] + wid * 2048;

  f32x4 acc[4][4] = {};

  int fr = lane & 15;
  int kg = (lane >> 4) * 8;

  // prologue: stage tile 0 into buffer 0
  {
    const unsigned short* a = gA0;
    const unsigned short* b = gB0;
    __builtin_amdgcn_global_load_lds((gas_ptr)(const void*)a, (las_ptr)(void*)ldsA0, 16, 0, 0);
    __builtin_amdgcn_global_load_lds((gas_ptr)(const void*)(a + 16 * HIDDEN), (las_ptr)(void*)(ldsA0 + 1024), 16, 0, 0);
    __builtin_amdgcn_global_load_lds((gas_ptr)(const void*)b, (las_ptr)(void*)ldsB0, 16, 0, 0);
    __builtin_amdgcn_global_load_lds((gas_ptr)(const void*)(b + 16 * HIDDEN), (las_ptr)(void*)(ldsB0 + 1024), 16, 0, 0);
  }

#pragma unroll
  for (int t = 0; t < NKSTEP; ++t) {
    int p = t & 1;
    if (t + 1 < NKSTEP) {
      int k1 = (t + 1) * GBK;
      const unsigned short* a = gA0 + k1;
      const unsigned short* b = gB0 + k1;
      char* dA = p ? ldsA0 : ldsA1;
      char* dB = p ? ldsB0 : ldsB1;
      __builtin_amdgcn_global_load_lds((gas_ptr)(const void*)a, (las_ptr)(void*)dA, 16, 0, 0);
      __builtin_amdgcn_global_load_lds((gas_ptr)(const void*)(a + 16 * HIDDEN), (las_ptr)(void*)(dA + 1024), 16, 0, 0);
      __builtin_amdgcn_global_load_lds((gas_ptr)(const void*)b, (las_ptr)(void*)dB, 16, 0, 0);
      __builtin_amdgcn_global_load_lds((gas_ptr)(const void*)(b + 16 * HIDDEN), (las_ptr)(void*)(dB + 1024), 16, 0, 0);
      asm volatile("s_waitcnt vmcnt(4)" ::: "memory");  // tile t's 4 loads done
    } else {
      asm volatile("s_waitcnt vmcnt(0)" ::: "memory");
    }
    __builtin_amdgcn_s_barrier();
    __builtin_amdgcn_sched_barrier(0);
    short8 af[4], bfg[4];
#pragma unroll
    for (int mi = 0; mi < 4; ++mi)
      af[mi] = *(const short8*)&As[p][wm * 64 + mi * 16 + fr][kg];
#pragma unroll
    for (int ni = 0; ni < 4; ++ni)
      bfg[ni] = *(const short8*)&Bs[p][wn * 64 + ni * 16 + fr][kg];
#pragma unroll
    for (int mi = 0; mi < 4; ++mi)
#pragma unroll
      for (int ni = 0; ni < 4; ++ni)
        acc[mi][ni] = __builtin_amdgcn_mfma_f32_16x16x32_bf16(af[mi], bfg[ni], acc[mi][ni], 0, 0, 0);
    __builtin_amdgcn_s_barrier();  // all waves done reading buf p before it is restaged
  }

  int fq = lane >> 4;
#pragma unroll
  for (int mi = 0; mi < 4; ++mi) {
#pragma unroll
    for (int ni = 0; ni < 4; ++ni) {
      int c = bcol + wn * 64 + ni * 16 + fr;
#pragma unroll
      for (int j = 0; j < 4; ++j) {
        int r = brow + wm * 64 + mi * 16 + fq * 4 + j;
        if (r < M) {
          float val = acc[mi][ni][j];
          if (MODE == 1) {
            Cf[(size_t)r * HIDDEN + c] = val + bias[c];
          } else {
            if (c < 256) Cq[(size_t)r * HIDDEN + c] = f2bf(val + bias[c]);
            else if (c < 512) Ck[(size_t)r * HIDDEN + (c - 256)] = f2bf(val);
            else Cv[(size_t)r * HIDDEN + (c - 512)] = f2bf(val);
          }
        }
      }
    }
  }
}

// ---------------- per-dst-node attention aggregation ----------------
// 1 wave per node. lane = 32*half + l; lane owns channels [l*8, l*8+8); head = l>>2.
// halves process edges idx+0 / idx+1 concurrently; combined at the end via shfl_xor(32).
__global__ __launch_bounds__(256) void agg_kernel(const unsigned short* __restrict__ q,
                                                  const unsigned short* __restrict__ k,
                                                  const unsigned short* __restrict__ v,
                                                  const int* __restrict__ offs,
                                                  const int* __restrict__ esrc,
                                                  unsigned short* __restrict__ o, int N) {
  int n = blockIdx.x * 4 + (threadIdx.x >> 6);
  if (n >= N) return;
  int lane = threadIdx.x & 63;
  int half = lane >> 5;
  int l = lane & 31;

  float qf[8];
  {
    ushort4 qa = *(const ushort4*)&q[(size_t)n * HIDDEN + l * 8];
    ushort4 qb = *(const ushort4*)&q[(size_t)n * HIDDEN + l * 8 + 4];
    qf[0] = bf2f(qa.x); qf[1] = bf2f(qa.y); qf[2] = bf2f(qa.z); qf[3] = bf2f(qa.w);
    qf[4] = bf2f(qb.x); qf[5] = bf2f(qb.y); qf[6] = bf2f(qb.z); qf[7] = bf2f(qb.w);
  }

  int e0 = offs[n], e1 = offs[n + 1];
  float wv[8] = {};
  float z = 0.f;

  for (int idx = e0; idx < e1; idx += 2) {
    int my = idx + half;
    bool valid = my < e1;
    int s = esrc[valid ? my : idx];
    const ushort4* kp = (const ushort4*)&k[(size_t)s * HIDDEN + l * 8];
    const ushort4* vp = (const ushort4*)&v[(size_t)s * HIDDEN + l * 8];
    ushort4 ka = kp[0], kb = kp[1];
    ushort4 va = vp[0], vb = vp[1];
    float dot = qf[0] * bf2f(ka.x) + qf[1] * bf2f(ka.y) + qf[2] * bf2f(ka.z) + qf[3] * bf2f(ka.w)
              + qf[4] * bf2f(kb.x) + qf[5] * bf2f(kb.y) + qf[6] * bf2f(kb.z) + qf[7] * bf2f(kb.w);
    dot += __shfl_xor(dot, 1);
    dot += __shfl_xor(dot, 2);   // full 32-ch head dot in all 4 lanes of the group
    float e = 0.f;
    if (valid) e = __expf(fminf(fmaxf(dot * INV_SCALE, -10.f), 10.f));
    wv[0] += e * bf2f(va.x); wv[1] += e * bf2f(va.y);
    wv[2] += e * bf2f(va.z); wv[3] += e * bf2f(va.w);
    wv[4] += e * bf2f(vb.x); wv[5] += e * bf2f(vb.y);
    wv[6] += e * bf2f(vb.z); wv[7] += e * bf2f(vb.w);
    z += e;
  }

  // combine the two halves
#pragma unroll
  for (int j = 0; j < 8; ++j) wv[j] += __shfl_xor(wv[j], 32);
  z += __shfl_xor(z, 32);

  if (half == 0) {
    float inv = 1.0f / z;
    ushort4 o0, o1;
    o0.x = f2bf(wv[0] * inv); o0.y = f2bf(wv[1] * inv);
    o0.z = f2bf(wv[2] * inv); o0.w = f2bf(wv[3] * inv);
    o1.x = f2bf(wv[4] * inv); o1.y = f2bf(wv[5] * inv);
    o1.z = f2bf(wv[6] * inv); o1.w = f2bf(wv[7] * inv);
    ushort4* op = (ushort4*)&o[(size_t)n * HIDDEN + l * 8];
    op[0] = o0; op[1] = o1;
  }
}

// ---------------- launch ----------------

extern "C" void kernel_launch(void* const* d_in, const int* in_sizes, int n_in,
                              void* d_out, int out_size, void* d_ws, size_t ws_size,
                              hipStream_t stream) {
  const float* inputs = (const float*)d_in[0];
  const float* Wq = (const float*)d_in[1];
  const float* bq = (const float*)d_in[2];
  const float* Wk = (const float*)d_in[3];
  const float* Wv = (const float*)d_in[4];
  const float* Wo = (const float*)d_in[5];
  const float* bo = (const float*)d_in[6];
  const int* src = (const int*)d_in[7];
  const int* dst = (const int*)d_in[8];

  int N = in_sizes[0] / HIDDEN;
  int E = in_sizes[7];
  int Mpad = N + GBM;  // pad rows so GEMM staging overrun stays in allocated ws

  char* w = (char*)d_ws;
  unsigned short* a_bf = (unsigned short*)w; w += (size_t)Mpad * HIDDEN * 2;
  unsigned short* qb = (unsigned short*)w;   w += (size_t)N * HIDDEN * 2;
  unsigned short* kb = (unsigned short*)w;   w += (size_t)N * HIDDEN * 2;
  unsigned short* vb = (unsigned short*)w;   w += (size_t)N * HIDDEN * 2;
  unsigned short* ob = (unsigned short*)w;   w += (size_t)Mpad * HIDDEN * 2;
  unsigned short* wqkv = (unsigned short*)w; w += (size_t)768 * HIDDEN * 2;
  unsigned short* wob = (unsigned short*)w;  w += (size_t)256 * HIDDEN * 2;
  int* deg = (int*)w;    w += (size_t)N * 4;
  int* offs = (int*)w;   w += (size_t)(N + 4) * 4;
  int* cursor = (int*)w; w += (size_t)N * 4;
  int* esrc = (int*)w;   w += (size_t)E * 4;
  int* bsums = (int*)w;  w += 256 * 4;

  // conversions
  conv_a_kernel<<<2048, 256, 0, stream>>>(inputs, a_bf, N * (HIDDEN / 4));
  conv_w_kernel<<<1024, 256, 0, stream>>>(Wq, Wk, Wv, Wo, wqkv, wob);

  // CSR build
  hipMemsetAsync(deg, 0, (size_t)N * 4, stream);
  int eb = (E + 255) / 256;
  hist_kernel<<<eb, 256, 0, stream>>>(dst, deg, E);
  int nb = (N + 1023) / 1024;
  scan1_kernel<<<nb, 256, 0, stream>>>(deg, offs, bsums, N);
  scan2_kernel<<<1, 64, 0, stream>>>(bsums, nb);
  scan3_kernel<<<(N + 255) / 256, 256, 0, stream>>>(offs, cursor, bsums, N, E);
  scatter_kernel<<<eb, 256, 0, stream>>>(dst, src, cursor, esrc, E);

  // fused QKV projection (bf16 MFMA)
  dim3 gqkv((N + GBM - 1) / GBM, 768 / GBN);
  mfma_gemm_kernel<0><<<gqkv, 256, 0, stream>>>(a_bf, wqkv, bq, nullptr, qb, kb, vb, N);

  // attention aggregation
  agg_kernel<<<(N + 3) / 4, 256, 0, stream>>>(qb, kb, vb, offs, esrc, ob, N);

  // output projection
  dim3 gout((N + GBM - 1) / GBM, 256 / GBN);
  mfma_gemm_kernel<1><<<gout, 256, 0, stream>>>(ob, wob, bo, (float*)d_out, nullptr, nullptr, nullptr, N);
}